// Round 8
// baseline (2034.412 us; speedup 1.0000x reference)
//
#include <hip/hip_runtime.h>
#include <math.h>

// ---------------------------------------------------------------------------
// AudioUNet5ConvLSTM — bf16 storage/f32 accum; MFMA for LSTM GEMMs and all
// inner conv/convT layers (implicit GEMM, BN folded into bf16 weights).
// R8: R7 + ONE isolated change — k_lstm_scan's two in-loop barriers are
// lgkm-only (s_waitcnt lgkmcnt(0); s_barrier), so the gx HBM prefetch and
// hs stores are never drained at a barrier. (R6 proved numerics-safe.)
// ---------------------------------------------------------------------------

#define WW 512
#define BB 16
#define TT 512

typedef unsigned short u16;
typedef __attribute__((ext_vector_type(8))) short bf16x8;
typedef __attribute__((ext_vector_type(4))) float f32x4;

__device__ __forceinline__ float sigm_(float x){ return 1.f/(1.f+__expf(-x)); }
__device__ __forceinline__ float tanh_(float x){ return 1.f - 2.f/(1.f+__expf(2.f*x)); }
__device__ __forceinline__ float b2f(u16 u){ return __uint_as_float(((unsigned)u)<<16); }
__device__ __forceinline__ u16 f2b(float f){
  unsigned x = __float_as_uint(f);
  return (u16)((x + 0x7fffu + ((x>>16)&1u)) >> 16);   // RNE
}
// LDS-only barrier: no vmcnt drain (global prefetch/stores stay in flight)
__device__ __forceinline__ void bar_lds(){
  asm volatile("s_waitcnt lgkmcnt(0)\n\ts_barrier" ::: "memory");
}

// ---------------- elementwise log10(x + 1e-8) -> bf16 ----------------
__global__ void k_log10(const float* __restrict__ x, u16* __restrict__ y, int n){
  int i = blockIdx.x*256 + threadIdx.x;
  if (i < n) y[i] = f2b(log10f(x[i] + 1e-8f));
}

// ---------------- enc1 (Cin=1) scalar: conv s(2,1) + BN + LReLU -------------
__global__ __launch_bounds__(128) void k_conv_enc(
    const u16* __restrict__ in, const float* __restrict__ w,
    const float* __restrict__ bias, const float* __restrict__ bg,
    const float* __restrict__ bb_, const float* __restrict__ bm,
    const float* __restrict__ bv, u16* __restrict__ out,
    int Cin, int Cout, int Hin, int Hout)
{
  int blk = blockIdx.x;
  int ho = blk % Hout; blk /= Hout;
  int co = blk % Cout; int b = blk / Cout;
  int t0 = threadIdx.x*4;
  float a0=0.f,a1=0.f,a2=0.f,a3=0.f;
  const float* wb = w + (size_t)co*Cin*9;
  for (int ci=0; ci<Cin; ++ci){
    const u16* ib = in + (size_t)(b*Cin+ci)*Hin*WW;
    const float* wc = wb + ci*9;
    #pragma unroll
    for (int kh=0; kh<3; ++kh){
      int hi = 2*ho + kh - 1;
      if (hi < 0 || hi >= Hin) continue;
      float w0 = wc[kh*3+0], w1 = wc[kh*3+1], w2 = wc[kh*3+2];
      const u16* row = ib + (size_t)hi*WW + t0;
      ushort4 xc = *(const ushort4*)row;
      float x0=b2f(xc.x), x1=b2f(xc.y), x2=b2f(xc.z), x3=b2f(xc.w);
      float xm = (t0==0)    ? 0.f : b2f(row[-1]);
      float xp = (t0+4>=WW) ? 0.f : b2f(row[4]);
      a0 += w0*xm + w1*x0 + w2*x1;
      a1 += w0*x0 + w1*x1 + w2*x2;
      a2 += w0*x1 + w1*x2 + w2*x3;
      a3 += w0*x2 + w1*x3 + w2*xp;
    }
  }
  float sc = bg[co]*rsqrtf(bv[co]+1e-5f);
  float sh = bb_[co] - bm[co]*sc + bias[co]*sc;
  float r0 = sc*a0+sh, r1 = sc*a1+sh, r2 = sc*a2+sh, r3 = sc*a3+sh;
  r0 = (r0>=0.f)?r0:0.2f*r0; r1 = (r1>=0.f)?r1:0.2f*r1;
  r2 = (r2>=0.f)?r2:0.2f*r2; r3 = (r3>=0.f)?r3:0.2f*r3;
  *(ushort4*)(out + ((size_t)((b*Cout+co)*Hout+ho))*WW + t0) =
      make_ushort4(f2b(r0), f2b(r1), f2b(r2), f2b(r3));
}

// ---------------- prep: encoder weights -> A[kw][co][KPAD] bf16, BN folded --
__global__ __launch_bounds__(256) void k_prep_enc(
    const float* __restrict__ w, const float* __restrict__ b,
    const float* __restrict__ g, const float* __restrict__ be,
    const float* __restrict__ m, const float* __restrict__ v,
    u16* __restrict__ A, float* __restrict__ bias2, int Cin, int Cout, int KPAD)
{
  int co = blockIdx.x;
  float sc = g[co]*rsqrtf(v[co]+1e-5f);
  if (threadIdx.x == 0) bias2[co] = be[co] - m[co]*sc + b[co]*sc;
  for (int idx = threadIdx.x; idx < 3*KPAD; idx += 256){
    int kw = idx / KPAD, k = idx - kw*KPAD;
    float val = 0.f;
    if (k < Cin*3){ int ci = k/3, kh = k - ci*3; val = w[(((size_t)co*Cin+ci)*3+kh)*3+kw]*sc; }
    A[(size_t)(kw*Cout+co)*KPAD + k] = f2b(val);
  }
}

// ---------------- prep: decoder weights (torch [Cin][Cout][3][3]) -----------
__global__ __launch_bounds__(256) void k_prep_dec(
    const float* __restrict__ w, const float* __restrict__ b,
    const float* __restrict__ g, const float* __restrict__ be,
    const float* __restrict__ m, const float* __restrict__ v,
    u16* __restrict__ AE, u16* __restrict__ AO, float* __restrict__ bias2,
    int Cin, int Cout)
{
  int co = blockIdx.x;
  float sc = g[co]*rsqrtf(v[co]+1e-5f);
  if (threadIdx.x == 0) bias2[co] = be[co] - m[co]*sc + b[co]*sc;
  for (int idx = threadIdx.x; idx < 3*Cin; idx += 256){
    int kw = idx / Cin, ci = idx - kw*Cin;
    const float* wp = w + ((size_t)ci*Cout + co)*9;
    AE[(size_t)(kw*Cout+co)*Cin + ci]          = f2b(wp[3+kw]*sc);   // kh=1
    AO[((size_t)(kw*Cout+co)*Cin + ci)*2 + 0]  = f2b(wp[6+kw]*sc);   // kh=2
    AO[((size_t)(kw*Cout+co)*Cin + ci)*2 + 1]  = f2b(wp[0+kw]*sc);   // kh=0
  }
}

// ---------------- implicit-GEMM MFMA conv / convT (R4 staging) --------------
template<int MT,int NT,int WMW,int WNW,int C1,int C2,int COUT,int HIN,int MODE,int MTL>
__global__ __launch_bounds__(256,2) void k_conv_mfma(
    const u16* __restrict__ inA, const u16* __restrict__ inB,
    const u16* __restrict__ AE, const u16* __restrict__ AO,
    const float* __restrict__ bias2, u16* __restrict__ out)
{
  constexpr int CIN  = C1 + C2;
  constexpr int HOUT = MODE ? HIN*2 : HIN/2;
  constexpr int KPAD0 = MODE ? CIN : ((C1*3+31)/32)*32;
  constexpr int LDK = 40;
  __shared__ __align__(16) u16 sB[130*LDK];
  int bi = blockIdx.x;
  int tt = bi & 3; bi >>= 2;
  int mt0 = 0;
  if (MTL == 2){ mt0 = bi & 1; bi >>= 1; }
  int ho = bi % HOUT, b = bi / HOUT;
  int t0 = tt*128;
  int tid = threadIdx.x;
  int w = tid>>6, L = tid&63, q = L>>4, n = L&15;
  int wm = w / WNW, wn = w % WNW;
  int co_base = (mt0*WMW + wm)*MT*16;
  int no = wn*NT*16;
  int odd = MODE ? (ho & 1) : 0;
  int nch     = MODE ? (odd ? CIN/16 : CIN/32) : KPAD0/32;
  int kstride = MODE ? (odd ? 2*CIN : CIN) : KPAD0;
  const u16* Ap = (MODE && odd) ? AO : AE;
  int kloc = tid>>3, seg = tid&7;
  f32x4 cfr[MT][NT];
  #pragma unroll
  for (int mt=0; mt<MT; ++mt)
    #pragma unroll
    for (int nt=0; nt<NT; ++nt){ cfr[mt][nt][0]=0.f; cfr[mt][nt][1]=0.f; cfr[mt][nt][2]=0.f; cfr[mt][nt][3]=0.f; }

  for (int kk=0; kk<nch; ++kk){
    int k = kk*32 + kloc;
    const u16* src = nullptr;
    if (MODE == 0){
      int ci = k/3, kh = k - 3*ci;
      int hi = 2*ho + kh - 1;
      if (k < C1*3 && hi >= 0 && hi < HIN)
        src = inA + ((size_t)(b*C1+ci)*HIN + hi)*WW;
    } else {
      int ci, hi;
      if (!odd){ ci = k; hi = ho>>1; }
      else { ci = k>>1; hi = (k&1) ? ((ho+1)>>1) : ((ho-1)>>1); }
      if (hi < HIN)
        src = (ci < C1) ? inA + ((size_t)(b*C1+ci)*HIN + hi)*WW
                        : inB + ((size_t)(b*C2+(ci-C1))*HIN + hi)*WW;
    }
    uint4 va = make_uint4(0,0,0,0), vb = make_uint4(0,0,0,0);
    u16 hl = 0, hr = 0;
    if (src){
      const u16* p = src + t0 + seg*16;
      va = *(const uint4*)p; vb = *(const uint4*)(p+8);
      if (seg==0 && t0 > 0)      hl = src[t0-1];
      if (seg==1 && t0+128 < WW) hr = src[t0+128];
    }
    __syncthreads();
    {
      const u16* s = (const u16*)&va;
      #pragma unroll
      for (int c=0;c<8;++c) sB[(1+seg*16+c)*LDK + kloc] = s[c];
      s = (const u16*)&vb;
      #pragma unroll
      for (int c=0;c<8;++c) sB[(9+seg*16+c)*LDK + kloc] = s[c];
      if (seg==0) sB[0*LDK + kloc]   = hl;
      if (seg==1) sB[129*LDK + kloc] = hr;
    }
    __syncthreads();
    #pragma unroll
    for (int kw=0; kw<3; ++kw){
      int tsh = MODE ? (2-kw) : kw;
      bf16x8 bfr[NT];
      #pragma unroll
      for (int nt=0; nt<NT; ++nt)
        bfr[nt] = *(const bf16x8*)(sB + (size_t)(no + nt*16 + n + tsh)*LDK + q*8);
      #pragma unroll
      for (int mt=0; mt<MT; ++mt){
        bf16x8 a = *(const bf16x8*)(Ap + ((size_t)(kw*COUT) + co_base + mt*16 + n)*kstride + kk*32 + q*8);
        #pragma unroll
        for (int nt=0; nt<NT; ++nt)
          cfr[mt][nt] = __builtin_amdgcn_mfma_f32_16x16x32_bf16(a, bfr[nt], cfr[mt][nt], 0,0,0);
      }
    }
  }
  #pragma unroll
  for (int mt=0; mt<MT; ++mt){
    #pragma unroll
    for (int r=0; r<4; ++r){
      int co = co_base + mt*16 + q*4 + r;
      float bs = bias2[co];
      #pragma unroll
      for (int nt=0; nt<NT; ++nt){
        float vv = cfr[mt][nt][r] + bs;
        vv = MODE ? fmaxf(vv, 0.f) : ((vv>=0.f)?vv:0.2f*vv);
        int t = t0 + no + nt*16 + n;
        out[((size_t)(b*COUT+co)*HOUT + ho)*WW + t] = f2b(vv);
      }
    }
  }
}

// ---------------- prep: pack lstm weights (kw=1 col) to bf16 GEMM layout ----
__global__ __launch_bounds__(256) void k_prep_w(
    const float* __restrict__ lstm_w, u16* __restrict__ Wxb, u16* __restrict__ Whb)
{
  int co = blockIdx.x;
  for (int k = threadIdx.x; k < 1152; k += 256){
    if (k < 768){
      int ci = k/3, kf = k - ci*3;
      Wxb[(size_t)co*768 + k] = f2b(lstm_w[((size_t)co*384 + ci)*9 + kf*3 + 1]);
    } else {
      int kh = k - 768;
      int ci = kh/3, kf = kh - ci*3;
      Whb[(size_t)co*384 + kh] = f2b(lstm_w[((size_t)co*384 + 256 + ci)*9 + kf*3 + 1]);
    }
  }
}

// ---------------- LSTM x-part as MFMA GEMM (R4 exact) -----------------------
__global__ __launch_bounds__(256,3) void k_xconv_mfma(
    const u16* __restrict__ e5, const u16* __restrict__ Wxb,
    const float* __restrict__ bias, u16* __restrict__ gt)
{
  __shared__ __align__(16) u16 smem[128*136];
  int bi = blockIdx.x;
  int tt = bi & 3, cot = (bi>>2) & 3, f = (bi>>4) & 7, b = bi>>7;
  int tid = threadIdx.x, w = tid>>6, L = tid&63, q = L>>4, n = L&15;
  int co_off = (w>>1)*64, t_off = (w&1)*64;
  int sr = tid>>3, sseg = tid&7;
  f32x4 cfr[4][4];
  #pragma unroll
  for (int i=0;i<4;++i)
    #pragma unroll
    for (int j=0;j<4;++j){ cfr[i][j][0]=0.f; cfr[i][j][1]=0.f; cfr[i][j][2]=0.f; cfr[i][j][3]=0.f; }
  const u16* e5b = e5 + (size_t)b*256*8*WW + tt*128 + sseg*16;
  const u16* ap0 = Wxb + (size_t)(cot*128 + co_off + n)*768 + q*8;

  for (int kk=0; kk<24; ++kk){
    int k0 = kk*32;
    {
      int k = k0 + sr;
      int ci = k/3, kf = k - ci*3, fi = f + kf - 1;
      union { uint4 v[2]; u16 s[16]; } uu;
      if (fi >= 0 && fi < 8){
        const u16* src = e5b + ((size_t)ci*8 + fi)*WW;
        uu.v[0] = *(const uint4*)src;
        uu.v[1] = *(const uint4*)(src+8);
      } else {
        uu.v[0] = make_uint4(0,0,0,0); uu.v[1] = make_uint4(0,0,0,0);
      }
      #pragma unroll
      for (int c=0;c<16;++c) smem[(sseg*16+c)*40 + sr] = uu.s[c];
    }
    __syncthreads();
    bf16x8 bfr[4];
    #pragma unroll
    for (int nt=0; nt<4; ++nt)
      bfr[nt] = *(const bf16x8*)(smem + (size_t)(t_off + nt*16 + n)*40 + q*8);
    #pragma unroll
    for (int mt=0; mt<4; ++mt){
      bf16x8 a = *(const bf16x8*)(ap0 + (size_t)mt*16*768 + k0);
      #pragma unroll
      for (int nt=0; nt<4; ++nt)
        cfr[mt][nt] = __builtin_amdgcn_mfma_f32_16x16x32_bf16(a, bfr[nt], cfr[mt][nt], 0,0,0);
    }
    __syncthreads();
  }
  #pragma unroll
  for (int mt=0; mt<4; ++mt){
    #pragma unroll
    for (int r2=0; r2<2; ++r2){
      int co_l = co_off + mt*16 + q*4 + r2*2;
      float bs0 = bias[cot*128 + co_l], bs1 = bias[cot*128 + co_l + 1];
      #pragma unroll
      for (int nt=0; nt<4; ++nt){
        int t_l = t_off + nt*16 + n;
        float v0 = cfr[mt][nt][r2*2]   + bs0;
        float v1 = cfr[mt][nt][r2*2+1] + bs1;
        unsigned pk = (unsigned)f2b(v0) | ((unsigned)f2b(v1)<<16);
        *(unsigned*)(smem + (size_t)t_l*136 + co_l) = pk;
      }
    }
  }
  __syncthreads();
  int row0 = tid>>6, lane2 = tid&63;
  size_t gbase = (((size_t)b*512 + tt*128)*8 + f)*512 + cot*128;
  for (int p=0; p<32; ++p){
    int t_l = p*4 + row0;
    unsigned v = *(const unsigned*)(smem + (size_t)t_l*136 + lane2*2);
    *(unsigned*)(gt + gbase + (size_t)t_l*8*512 + lane2*2) = v;
  }
}

// ---------------- sequential LSTM scan (R5 + lgkm-only in-loop barriers) ----
__global__ __launch_bounds__(512,2) void k_lstm_scan(
    const u16* __restrict__ gt, const u16* __restrict__ Whb,
    u16* __restrict__ hs)
{
  __shared__ __align__(16) u16 Bl[6144+16];
  __shared__ float Gl[512*9];
  int b = blockIdx.x;
  int tid = threadIdx.x, w = tid>>6, L = tid&63, q = L>>4, n = L&15;
  int ch = tid>>2, fa = tid&3, fb = fa|4;
  for (int i = tid; i < 6144+16; i += 512) Bl[i] = 0;
  bf16x8 afr[48];
  #pragma unroll
  for (int mt=0; mt<4; ++mt){
    const u16* ap = Whb + (size_t)(w*64 + mt*16 + n)*384 + q*8;
    #pragma unroll
    for (int kt=0; kt<12; ++kt)
      afr[mt*12+kt] = *(const bf16x8*)(ap + kt*32);
  }
  int sa[6];
  #pragma unroll
  for (int i2=0;i2<2;++i2){
    int fi = i2 ? fb : fa;
    #pragma unroll
    for (int kf=0;kf<3;++kf){
      int ff = fi + 1 - kf;
      int k = ch*3 + kf;
      sa[i2*3+kf] = (ff>=0 && ff<8)
          ? (((k>>5)*4 + ((k>>3)&3))*128 + ff*8 + (k&7))
          : (6144 + (tid&7));
    }
  }
  float c0 = 0.f, c1 = 0.f;
  __syncthreads();
  const size_t gbase = (size_t)b*512;
  const u16* pa = gt + gbase*4096 + fa*512 + ch;
  const u16* pb = gt + gbase*4096 + fb*512 + ch;
  u16 gc[8];
  #pragma unroll
  for (int g=0; g<4; ++g){ gc[g] = pa[g*128]; gc[4+g] = pb[g*128]; }
  for (int t=0; t<TT; ++t){
    u16 gn[8];
    {
      int tc = (t+1 < TT) ? (t+1) : t;
      const u16* qa = pa + (size_t)tc*4096;
      const u16* qb = pb + (size_t)tc*4096;
      #pragma unroll
      for (int g=0; g<4; ++g){ gn[g] = qa[g*128]; gn[4+g] = qb[g*128]; }
    }
    f32x4 cfr[4];
    #pragma unroll
    for (int mt=0; mt<4; ++mt){ cfr[mt][0]=0.f; cfr[mt][1]=0.f; cfr[mt][2]=0.f; cfr[mt][3]=0.f; }
    #pragma unroll
    for (int kt=0; kt<12; ++kt){
      bf16x8 bfr = *(const bf16x8*)(Bl + ((kt*4+q)*16 + n)*8);
      #pragma unroll
      for (int mt=0; mt<4; ++mt)
        cfr[mt] = __builtin_amdgcn_mfma_f32_16x16x32_bf16(afr[mt*12+kt], bfr, cfr[mt], 0,0,0);
    }
    if (n < 8){
      #pragma unroll
      for (int mt=0; mt<4; ++mt){
        int co = w*64 + mt*16 + q*4;
        #pragma unroll
        for (int r=0; r<4; ++r) Gl[(co+r)*9 + n] = cfr[mt][r];
      }
    }
    bar_lds();
    float i0 = Gl[ ch      *9 + fa] + b2f(gc[0]);
    float f0 = Gl[(128+ch)*9 + fa] + b2f(gc[1]);
    float o0 = Gl[(256+ch)*9 + fa] + b2f(gc[2]);
    float g0 = Gl[(384+ch)*9 + fa] + b2f(gc[3]);
    float i1 = Gl[ ch      *9 + fb] + b2f(gc[4]);
    float f1 = Gl[(128+ch)*9 + fb] + b2f(gc[5]);
    float o1 = Gl[(256+ch)*9 + fb] + b2f(gc[6]);
    float g1 = Gl[(384+ch)*9 + fb] + b2f(gc[7]);
    c0 = sigm_(f0)*c0 + sigm_(i0)*tanh_(g0);
    c1 = sigm_(f1)*c1 + sigm_(i1)*tanh_(g1);
    float h0 = sigm_(o0)*tanh_(c0);
    float h1 = sigm_(o1)*tanh_(c1);
    u16 hb0 = f2b(h0), hb1 = f2b(h1);
    u16* op = hs + ((gbase + t)*128 + ch)*8;
    op[fa] = hb0;
    op[fb] = hb1;
    Bl[sa[0]] = hb0; Bl[sa[1]] = hb0; Bl[sa[2]] = hb0;
    Bl[sa[3]] = hb1; Bl[sa[4]] = hb1; Bl[sa[5]] = hb1;
    bar_lds();
    #pragma unroll
    for (int g=0; g<8; ++g) gc[g] = gn[g];
  }
}

// ---------------- batched u16 transpose [b][R][C] -> [b][C][R] --------------
__global__ __launch_bounds__(256) void k_transpose_u16(
    const u16* __restrict__ in, u16* __restrict__ out, int R, int C)
{
  __shared__ u16 tile[32][33];
  int b = blockIdx.z;
  const u16* ip = in  + (size_t)b*R*C;
  u16*       op = out + (size_t)b*R*C;
  int c0 = blockIdx.x*32, r0 = blockIdx.y*32;
  #pragma unroll
  for (int i = threadIdx.y; i < 32; i += 8)
    tile[i][threadIdx.x] = ip[(size_t)(r0+i)*C + (c0+threadIdx.x)];
  __syncthreads();
  #pragma unroll
  for (int i = threadIdx.y; i < 32; i += 8)
    op[(size_t)(c0+i)*R + (r0+threadIdx.x)] = tile[threadIdx.x][i];
}

// ---------------- dec1 scalar: convT + sigmoid + x*mask ---------------------
__global__ __launch_bounds__(128) void k_convT(
    const u16* __restrict__ inA, int C1,
    const u16* __restrict__ inB, int C2,
    const float* __restrict__ w, const float* __restrict__ bias,
    const float* __restrict__ xorig, float* __restrict__ fout,
    int Cout, int Hin)
{
  int Hout = Hin*2;
  int blk = blockIdx.x;
  int y = blk % Hout; blk /= Hout;
  int co = blk % Cout; int b = blk / Cout;
  int t0 = threadIdx.x*4;
  int Cin = C1 + C2;
  int kh0, hi0, kh1 = -1, hi1 = 0;
  if ((y&1)==0){ kh0 = 1; hi0 = y>>1; }
  else { kh0 = 2; hi0 = (y-1)>>1; int h1 = (y+1)>>1; if (h1 < Hin){ kh1 = 0; hi1 = h1; } }
  float a0=0.f,a1=0.f,a2=0.f,a3=0.f;
  for (int ci=0; ci<Cin; ++ci){
    const u16* ib = (ci<C1) ? inA + (size_t)(b*C1+ci)*Hin*WW
                            : inB + (size_t)(b*C2+(ci-C1))*Hin*WW;
    const float* wc = w + ((size_t)ci*Cout + co)*9;
    {
      float w0 = wc[kh0*3+0], w1 = wc[kh0*3+1], w2 = wc[kh0*3+2];
      const u16* row = ib + (size_t)hi0*WW + t0;
      ushort4 xc = *(const ushort4*)row;
      float x0=b2f(xc.x), x1=b2f(xc.y), x2=b2f(xc.z), x3=b2f(xc.w);
      float xm = (t0==0)    ? 0.f : b2f(row[-1]);
      float xp = (t0+4>=WW) ? 0.f : b2f(row[4]);
      a0 += w2*xm + w1*x0 + w0*x1;
      a1 += w2*x0 + w1*x1 + w0*x2;
      a2 += w2*x1 + w1*x2 + w0*x3;
      a3 += w2*x2 + w1*x3 + w0*xp;
    }
    if (kh1 >= 0){
      float w0 = wc[0], w1 = wc[1], w2 = wc[2];
      const u16* row = ib + (size_t)hi1*WW + t0;
      ushort4 xc = *(const ushort4*)row;
      float x0=b2f(xc.x), x1=b2f(xc.y), x2=b2f(xc.z), x3=b2f(xc.w);
      float xm = (t0==0)    ? 0.f : b2f(row[-1]);
      float xp = (t0+4>=WW) ? 0.f : b2f(row[4]);
      a0 += w2*xm + w1*x0 + w0*x1;
      a1 += w2*x0 + w1*x1 + w0*x2;
      a2 += w2*x1 + w1*x2 + w0*x3;
      a3 += w2*x2 + w1*x3 + w0*xp;
    }
  }
  size_t opos = ((size_t)((b*Cout+co)*Hout + y))*WW + t0;
  float bi = bias[co];
  const float4 xv = *(const float4*)(xorig + ((size_t)(b*256 + y))*WW + t0);
  float4 o;
  o.x = xv.x * sigm_(a0+bi); o.y = xv.y * sigm_(a1+bi);
  o.z = xv.z * sigm_(a2+bi); o.w = xv.w * sigm_(a3+bi);
  *(float4*)(fout + opos) = o;
}

// ---------------------------------------------------------------------------
extern "C" void kernel_launch(void* const* d_in, const int* in_sizes, int n_in,
                              void* d_out, int out_size, void* d_ws, size_t ws_size,
                              hipStream_t stream) {
  const float* x = (const float*)d_in[0];
  struct Blk { const float *w,*b,*g,*be,*m,*v; };
  auto grab = [&](int p){ return Blk{ (const float*)d_in[p], (const float*)d_in[p+1],
                                      (const float*)d_in[p+2], (const float*)d_in[p+3],
                                      (const float*)d_in[p+4], (const float*)d_in[p+5] }; };
  Blk enc1 = grab(1), enc2 = grab(7), enc3 = grab(13), enc4 = grab(19), enc5 = grab(25);
  const float* lstm_w = (const float*)d_in[31];
  const float* lstm_b = (const float*)d_in[32];
  Blk dec5 = grab(33), dec4 = grab(39), dec3 = grab(45), dec2 = grab(51);
  const float* dec1_w = (const float*)d_in[57];
  const float* dec1_b = (const float*)d_in[58];

  // ---- 228 MiB arena, lifetime-aliased ----
  char* ws = (char*)d_ws;
  #define MBOF(x) ((size_t)(x)*1048576ULL)
  u16*   xlog = (u16*)  (ws + MBOF(0));
  u16*   Wxb  = (u16*)  (ws + MBOF(0));
  u16*   Whb  = (u16*)  (ws + MBOF(1));
  char*  P0   =          ws + 1572864;
  u16*   e1   = (u16*)  (ws + MBOF(4));
  u16*   e2   = (u16*)  (ws + MBOF(36));
  u16*   e3   = (u16*)  (ws + MBOF(68));
  u16*   e4   = (u16*)  (ws + MBOF(100));
  u16*   e5   = (u16*)  (ws + MBOF(132));
  u16*   hst  = (u16*)  (ws + MBOF(132));
  u16*   lout = (u16*)  (ws + MBOF(148));
  u16*   gt   = (u16*)  (ws + MBOF(164));
  u16*   d5   = (u16*)  (ws + MBOF(164));
  u16*   d4   = (u16*)  (ws + MBOF(132));
  u16*   d3   = (u16*)  (ws + MBOF(196));
  u16*   d2   = (u16*)  (ws + MBOF(164));

  u16* encA2 = (u16*)(P0 + 0);       u16* encA3 = (u16*)(P0 + 12288);
  u16* encA4 = (u16*)(P0 + 49152);   u16* encA5 = (u16*)(P0 + 196608);
  u16* decE5 = (u16*)(P0 + 786432);  u16* decO5 = (u16*)(P0 + 884736);
  u16* decE4 = (u16*)(P0 + 1081344); u16* decO4 = (u16*)(P0 + 1179648);
  u16* decE3 = (u16*)(P0 + 1376256); u16* decO3 = (u16*)(P0 + 1400832);
  u16* decE2 = (u16*)(P0 + 1449984); u16* decO2 = (u16*)(P0 + 1456128);
  float* bE2 = (float*)(P0 + 1468416); float* bE3 = (float*)(P0 + 1469440);
  float* bE4 = (float*)(P0 + 1470464); float* bE5 = (float*)(P0 + 1471488);
  float* bD5 = (float*)(P0 + 1472512); float* bD4 = (float*)(P0 + 1473536);
  float* bD3 = (float*)(P0 + 1474560); float* bD2 = (float*)(P0 + 1475584);

  // 1. log10 + enc1 (scalar)
  { int n = BB*256*WW; k_log10<<<(n+255)/256, 256, 0, stream>>>(x, xlog, n); }
  k_conv_enc<<<BB*16*128, 128, 0, stream>>>(xlog, enc1.w, enc1.b, enc1.g, enc1.be, enc1.m, enc1.v, e1, 1, 16, 256, 128);
  // 2. weight prep (xlog region dead now)
  k_prep_w<<<512, 256, 0, stream>>>(lstm_w, Wxb, Whb);
  k_prep_enc<<<32,  256, 0, stream>>>(enc2.w, enc2.b, enc2.g, enc2.be, enc2.m, enc2.v, encA2, bE2, 16, 32, 64);
  k_prep_enc<<<64,  256, 0, stream>>>(enc3.w, enc3.b, enc3.g, enc3.be, enc3.m, enc3.v, encA3, bE3, 32, 64, 96);
  k_prep_enc<<<128, 256, 0, stream>>>(enc4.w, enc4.b, enc4.g, enc4.be, enc4.m, enc4.v, encA4, bE4, 64, 128, 192);
  k_prep_enc<<<256, 256, 0, stream>>>(enc5.w, enc5.b, enc5.g, enc5.be, enc5.m, enc5.v, encA5, bE5, 128, 256, 384);
  k_prep_dec<<<128, 256, 0, stream>>>(dec5.w, dec5.b, dec5.g, dec5.be, dec5.m, dec5.v, decE5, decO5, bD5, 128, 128);
  k_prep_dec<<<64,  256, 0, stream>>>(dec4.w, dec4.b, dec4.g, dec4.be, dec4.m, dec4.v, decE4, decO4, bD4, 256, 64);
  k_prep_dec<<<32,  256, 0, stream>>>(dec3.w, dec3.b, dec3.g, dec3.be, dec3.m, dec3.v, decE3, decO3, bD3, 128, 32);
  k_prep_dec<<<16,  256, 0, stream>>>(dec2.w, dec2.b, dec2.g, dec2.be, dec2.m, dec2.v, decE2, decO2, bD2, 64, 16);
  // 3. encoder (MFMA implicit GEMM)
  k_conv_mfma<2,2,1,4, 16,0, 32,128,0,1><<<BB*64*4,   256, 0, stream>>>(e1, e1, encA2, encA2, bE2, e2);
  k_conv_mfma<4,2,1,4, 32,0, 64, 64,0,1><<<BB*32*4,   256, 0, stream>>>(e2, e2, encA3, encA3, bE3, e3);
  k_conv_mfma<4,4,2,2, 64,0,128, 32,0,1><<<BB*16*4,   256, 0, stream>>>(e3, e3, encA4, encA4, bE4, e4);
  k_conv_mfma<4,4,2,2,128,0,256, 16,0,2><<<BB*8*2*4,  256, 0, stream>>>(e4, e4, encA5, encA5, bE5, e5);
  // 4. LSTM
  k_xconv_mfma<<<BB*8*16, 256, 0, stream>>>(e5, Wxb, lstm_b, gt);
  k_lstm_scan<<<BB, 512, 0, stream>>>(gt, Whb, hst);
  k_transpose_u16<<<dim3(1024/32, 512/32, BB), dim3(32,8), 0, stream>>>(hst, lout, 512, 1024);
  // 5. decoder (MFMA implicit GEMM) + dec1 scalar
  k_conv_mfma<4,4,2,2,128,  0,128,  8,1,1><<<BB*16*4,  256, 0, stream>>>(lout, lout, decE5, decO5, bD5, d5);
  k_conv_mfma<4,2,1,4,128,128, 64, 16,1,1><<<BB*32*4,  256, 0, stream>>>(d5, e4, decE4, decO4, bD4, d4);
  k_conv_mfma<2,2,1,4, 64, 64, 32, 32,1,1><<<BB*64*4,  256, 0, stream>>>(d4, e3, decE3, decO3, bD3, d3);
  k_conv_mfma<1,2,1,4, 32, 32, 16, 64,1,1><<<BB*128*4, 256, 0, stream>>>(d3, e2, decE2, decO2, bD2, d2);
  k_convT<<<BB*1*256, 128, 0, stream>>>(d2, 16, e1, 16, dec1_w, dec1_b, x, (float*)d_out, 1, 128);
}

// Round 9
// 1993.865 us; speedup vs baseline: 1.0203x; 1.0203x over previous
//
#include <hip/hip_runtime.h>
#include <math.h>

// ---------------------------------------------------------------------------
// AudioUNet5ConvLSTM — bf16 storage/f32 accum; MFMA for LSTM GEMMs and all
// inner conv/convT layers (implicit GEMM, BN folded into bf16 weights).
// R9: R8 + ONE isolated change — k_lstm_scan hoists all 12 B-fragment
// ds_read_b128 loads ahead of the MFMA chains (batched reads, staged
// lgkmcnt) and batches the 8 Gl epilogue reads into locals.
// ---------------------------------------------------------------------------

#define WW 512
#define BB 16
#define TT 512

typedef unsigned short u16;
typedef __attribute__((ext_vector_type(8))) short bf16x8;
typedef __attribute__((ext_vector_type(4))) float f32x4;

__device__ __forceinline__ float sigm_(float x){ return 1.f/(1.f+__expf(-x)); }
__device__ __forceinline__ float tanh_(float x){ return 1.f - 2.f/(1.f+__expf(2.f*x)); }
__device__ __forceinline__ float b2f(u16 u){ return __uint_as_float(((unsigned)u)<<16); }
__device__ __forceinline__ u16 f2b(float f){
  unsigned x = __float_as_uint(f);
  return (u16)((x + 0x7fffu + ((x>>16)&1u)) >> 16);   // RNE
}
// LDS-only barrier: no vmcnt drain (global prefetch/stores stay in flight)
__device__ __forceinline__ void bar_lds(){
  asm volatile("s_waitcnt lgkmcnt(0)\n\ts_barrier" ::: "memory");
}

// ---------------- elementwise log10(x + 1e-8) -> bf16 ----------------
__global__ void k_log10(const float* __restrict__ x, u16* __restrict__ y, int n){
  int i = blockIdx.x*256 + threadIdx.x;
  if (i < n) y[i] = f2b(log10f(x[i] + 1e-8f));
}

// ---------------- enc1 (Cin=1) scalar: conv s(2,1) + BN + LReLU -------------
__global__ __launch_bounds__(128) void k_conv_enc(
    const u16* __restrict__ in, const float* __restrict__ w,
    const float* __restrict__ bias, const float* __restrict__ bg,
    const float* __restrict__ bb_, const float* __restrict__ bm,
    const float* __restrict__ bv, u16* __restrict__ out,
    int Cin, int Cout, int Hin, int Hout)
{
  int blk = blockIdx.x;
  int ho = blk % Hout; blk /= Hout;
  int co = blk % Cout; int b = blk / Cout;
  int t0 = threadIdx.x*4;
  float a0=0.f,a1=0.f,a2=0.f,a3=0.f;
  const float* wb = w + (size_t)co*Cin*9;
  for (int ci=0; ci<Cin; ++ci){
    const u16* ib = in + (size_t)(b*Cin+ci)*Hin*WW;
    const float* wc = wb + ci*9;
    #pragma unroll
    for (int kh=0; kh<3; ++kh){
      int hi = 2*ho + kh - 1;
      if (hi < 0 || hi >= Hin) continue;
      float w0 = wc[kh*3+0], w1 = wc[kh*3+1], w2 = wc[kh*3+2];
      const u16* row = ib + (size_t)hi*WW + t0;
      ushort4 xc = *(const ushort4*)row;
      float x0=b2f(xc.x), x1=b2f(xc.y), x2=b2f(xc.z), x3=b2f(xc.w);
      float xm = (t0==0)    ? 0.f : b2f(row[-1]);
      float xp = (t0+4>=WW) ? 0.f : b2f(row[4]);
      a0 += w0*xm + w1*x0 + w2*x1;
      a1 += w0*x0 + w1*x1 + w2*x2;
      a2 += w0*x1 + w1*x2 + w2*x3;
      a3 += w0*x2 + w1*x3 + w2*xp;
    }
  }
  float sc = bg[co]*rsqrtf(bv[co]+1e-5f);
  float sh = bb_[co] - bm[co]*sc + bias[co]*sc;
  float r0 = sc*a0+sh, r1 = sc*a1+sh, r2 = sc*a2+sh, r3 = sc*a3+sh;
  r0 = (r0>=0.f)?r0:0.2f*r0; r1 = (r1>=0.f)?r1:0.2f*r1;
  r2 = (r2>=0.f)?r2:0.2f*r2; r3 = (r3>=0.f)?r3:0.2f*r3;
  *(ushort4*)(out + ((size_t)((b*Cout+co)*Hout+ho))*WW + t0) =
      make_ushort4(f2b(r0), f2b(r1), f2b(r2), f2b(r3));
}

// ---------------- prep: encoder weights -> A[kw][co][KPAD] bf16, BN folded --
__global__ __launch_bounds__(256) void k_prep_enc(
    const float* __restrict__ w, const float* __restrict__ b,
    const float* __restrict__ g, const float* __restrict__ be,
    const float* __restrict__ m, const float* __restrict__ v,
    u16* __restrict__ A, float* __restrict__ bias2, int Cin, int Cout, int KPAD)
{
  int co = blockIdx.x;
  float sc = g[co]*rsqrtf(v[co]+1e-5f);
  if (threadIdx.x == 0) bias2[co] = be[co] - m[co]*sc + b[co]*sc;
  for (int idx = threadIdx.x; idx < 3*KPAD; idx += 256){
    int kw = idx / KPAD, k = idx - kw*KPAD;
    float val = 0.f;
    if (k < Cin*3){ int ci = k/3, kh = k - ci*3; val = w[(((size_t)co*Cin+ci)*3+kh)*3+kw]*sc; }
    A[(size_t)(kw*Cout+co)*KPAD + k] = f2b(val);
  }
}

// ---------------- prep: decoder weights (torch [Cin][Cout][3][3]) -----------
__global__ __launch_bounds__(256) void k_prep_dec(
    const float* __restrict__ w, const float* __restrict__ b,
    const float* __restrict__ g, const float* __restrict__ be,
    const float* __restrict__ m, const float* __restrict__ v,
    u16* __restrict__ AE, u16* __restrict__ AO, float* __restrict__ bias2,
    int Cin, int Cout)
{
  int co = blockIdx.x;
  float sc = g[co]*rsqrtf(v[co]+1e-5f);
  if (threadIdx.x == 0) bias2[co] = be[co] - m[co]*sc + b[co]*sc;
  for (int idx = threadIdx.x; idx < 3*Cin; idx += 256){
    int kw = idx / Cin, ci = idx - kw*Cin;
    const float* wp = w + ((size_t)ci*Cout + co)*9;
    AE[(size_t)(kw*Cout+co)*Cin + ci]          = f2b(wp[3+kw]*sc);   // kh=1
    AO[((size_t)(kw*Cout+co)*Cin + ci)*2 + 0]  = f2b(wp[6+kw]*sc);   // kh=2
    AO[((size_t)(kw*Cout+co)*Cin + ci)*2 + 1]  = f2b(wp[0+kw]*sc);   // kh=0
  }
}

// ---------------- implicit-GEMM MFMA conv / convT (R4 staging) --------------
template<int MT,int NT,int WMW,int WNW,int C1,int C2,int COUT,int HIN,int MODE,int MTL>
__global__ __launch_bounds__(256,2) void k_conv_mfma(
    const u16* __restrict__ inA, const u16* __restrict__ inB,
    const u16* __restrict__ AE, const u16* __restrict__ AO,
    const float* __restrict__ bias2, u16* __restrict__ out)
{
  constexpr int CIN  = C1 + C2;
  constexpr int HOUT = MODE ? HIN*2 : HIN/2;
  constexpr int KPAD0 = MODE ? CIN : ((C1*3+31)/32)*32;
  constexpr int LDK = 40;
  __shared__ __align__(16) u16 sB[130*LDK];
  int bi = blockIdx.x;
  int tt = bi & 3; bi >>= 2;
  int mt0 = 0;
  if (MTL == 2){ mt0 = bi & 1; bi >>= 1; }
  int ho = bi % HOUT, b = bi / HOUT;
  int t0 = tt*128;
  int tid = threadIdx.x;
  int w = tid>>6, L = tid&63, q = L>>4, n = L&15;
  int wm = w / WNW, wn = w % WNW;
  int co_base = (mt0*WMW + wm)*MT*16;
  int no = wn*NT*16;
  int odd = MODE ? (ho & 1) : 0;
  int nch     = MODE ? (odd ? CIN/16 : CIN/32) : KPAD0/32;
  int kstride = MODE ? (odd ? 2*CIN : CIN) : KPAD0;
  const u16* Ap = (MODE && odd) ? AO : AE;
  int kloc = tid>>3, seg = tid&7;
  f32x4 cfr[MT][NT];
  #pragma unroll
  for (int mt=0; mt<MT; ++mt)
    #pragma unroll
    for (int nt=0; nt<NT; ++nt){ cfr[mt][nt][0]=0.f; cfr[mt][nt][1]=0.f; cfr[mt][nt][2]=0.f; cfr[mt][nt][3]=0.f; }

  for (int kk=0; kk<nch; ++kk){
    int k = kk*32 + kloc;
    const u16* src = nullptr;
    if (MODE == 0){
      int ci = k/3, kh = k - 3*ci;
      int hi = 2*ho + kh - 1;
      if (k < C1*3 && hi >= 0 && hi < HIN)
        src = inA + ((size_t)(b*C1+ci)*HIN + hi)*WW;
    } else {
      int ci, hi;
      if (!odd){ ci = k; hi = ho>>1; }
      else { ci = k>>1; hi = (k&1) ? ((ho+1)>>1) : ((ho-1)>>1); }
      if (hi < HIN)
        src = (ci < C1) ? inA + ((size_t)(b*C1+ci)*HIN + hi)*WW
                        : inB + ((size_t)(b*C2+(ci-C1))*HIN + hi)*WW;
    }
    uint4 va = make_uint4(0,0,0,0), vb = make_uint4(0,0,0,0);
    u16 hl = 0, hr = 0;
    if (src){
      const u16* p = src + t0 + seg*16;
      va = *(const uint4*)p; vb = *(const uint4*)(p+8);
      if (seg==0 && t0 > 0)      hl = src[t0-1];
      if (seg==1 && t0+128 < WW) hr = src[t0+128];
    }
    __syncthreads();
    {
      const u16* s = (const u16*)&va;
      #pragma unroll
      for (int c=0;c<8;++c) sB[(1+seg*16+c)*LDK + kloc] = s[c];
      s = (const u16*)&vb;
      #pragma unroll
      for (int c=0;c<8;++c) sB[(9+seg*16+c)*LDK + kloc] = s[c];
      if (seg==0) sB[0*LDK + kloc]   = hl;
      if (seg==1) sB[129*LDK + kloc] = hr;
    }
    __syncthreads();
    #pragma unroll
    for (int kw=0; kw<3; ++kw){
      int tsh = MODE ? (2-kw) : kw;
      bf16x8 bfr[NT];
      #pragma unroll
      for (int nt=0; nt<NT; ++nt)
        bfr[nt] = *(const bf16x8*)(sB + (size_t)(no + nt*16 + n + tsh)*LDK + q*8);
      #pragma unroll
      for (int mt=0; mt<MT; ++mt){
        bf16x8 a = *(const bf16x8*)(Ap + ((size_t)(kw*COUT) + co_base + mt*16 + n)*kstride + kk*32 + q*8);
        #pragma unroll
        for (int nt=0; nt<NT; ++nt)
          cfr[mt][nt] = __builtin_amdgcn_mfma_f32_16x16x32_bf16(a, bfr[nt], cfr[mt][nt], 0,0,0);
      }
    }
  }
  #pragma unroll
  for (int mt=0; mt<MT; ++mt){
    #pragma unroll
    for (int r=0; r<4; ++r){
      int co = co_base + mt*16 + q*4 + r;
      float bs = bias2[co];
      #pragma unroll
      for (int nt=0; nt<NT; ++nt){
        float vv = cfr[mt][nt][r] + bs;
        vv = MODE ? fmaxf(vv, 0.f) : ((vv>=0.f)?vv:0.2f*vv);
        int t = t0 + no + nt*16 + n;
        out[((size_t)(b*COUT+co)*HOUT + ho)*WW + t] = f2b(vv);
      }
    }
  }
}

// ---------------- prep: pack lstm weights (kw=1 col) to bf16 GEMM layout ----
__global__ __launch_bounds__(256) void k_prep_w(
    const float* __restrict__ lstm_w, u16* __restrict__ Wxb, u16* __restrict__ Whb)
{
  int co = blockIdx.x;
  for (int k = threadIdx.x; k < 1152; k += 256){
    if (k < 768){
      int ci = k/3, kf = k - ci*3;
      Wxb[(size_t)co*768 + k] = f2b(lstm_w[((size_t)co*384 + ci)*9 + kf*3 + 1]);
    } else {
      int kh = k - 768;
      int ci = kh/3, kf = kh - ci*3;
      Whb[(size_t)co*384 + kh] = f2b(lstm_w[((size_t)co*384 + 256 + ci)*9 + kf*3 + 1]);
    }
  }
}

// ---------------- LSTM x-part as MFMA GEMM (R4 exact) -----------------------
__global__ __launch_bounds__(256,3) void k_xconv_mfma(
    const u16* __restrict__ e5, const u16* __restrict__ Wxb,
    const float* __restrict__ bias, u16* __restrict__ gt)
{
  __shared__ __align__(16) u16 smem[128*136];
  int bi = blockIdx.x;
  int tt = bi & 3, cot = (bi>>2) & 3, f = (bi>>4) & 7, b = bi>>7;
  int tid = threadIdx.x, w = tid>>6, L = tid&63, q = L>>4, n = L&15;
  int co_off = (w>>1)*64, t_off = (w&1)*64;
  int sr = tid>>3, sseg = tid&7;
  f32x4 cfr[4][4];
  #pragma unroll
  for (int i=0;i<4;++i)
    #pragma unroll
    for (int j=0;j<4;++j){ cfr[i][j][0]=0.f; cfr[i][j][1]=0.f; cfr[i][j][2]=0.f; cfr[i][j][3]=0.f; }
  const u16* e5b = e5 + (size_t)b*256*8*WW + tt*128 + sseg*16;
  const u16* ap0 = Wxb + (size_t)(cot*128 + co_off + n)*768 + q*8;

  for (int kk=0; kk<24; ++kk){
    int k0 = kk*32;
    {
      int k = k0 + sr;
      int ci = k/3, kf = k - ci*3, fi = f + kf - 1;
      union { uint4 v[2]; u16 s[16]; } uu;
      if (fi >= 0 && fi < 8){
        const u16* src = e5b + ((size_t)ci*8 + fi)*WW;
        uu.v[0] = *(const uint4*)src;
        uu.v[1] = *(const uint4*)(src+8);
      } else {
        uu.v[0] = make_uint4(0,0,0,0); uu.v[1] = make_uint4(0,0,0,0);
      }
      #pragma unroll
      for (int c=0;c<16;++c) smem[(sseg*16+c)*40 + sr] = uu.s[c];
    }
    __syncthreads();
    bf16x8 bfr[4];
    #pragma unroll
    for (int nt=0; nt<4; ++nt)
      bfr[nt] = *(const bf16x8*)(smem + (size_t)(t_off + nt*16 + n)*40 + q*8);
    #pragma unroll
    for (int mt=0; mt<4; ++mt){
      bf16x8 a = *(const bf16x8*)(ap0 + (size_t)mt*16*768 + k0);
      #pragma unroll
      for (int nt=0; nt<4; ++nt)
        cfr[mt][nt] = __builtin_amdgcn_mfma_f32_16x16x32_bf16(a, bfr[nt], cfr[mt][nt], 0,0,0);
    }
    __syncthreads();
  }
  #pragma unroll
  for (int mt=0; mt<4; ++mt){
    #pragma unroll
    for (int r2=0; r2<2; ++r2){
      int co_l = co_off + mt*16 + q*4 + r2*2;
      float bs0 = bias[cot*128 + co_l], bs1 = bias[cot*128 + co_l + 1];
      #pragma unroll
      for (int nt=0; nt<4; ++nt){
        int t_l = t_off + nt*16 + n;
        float v0 = cfr[mt][nt][r2*2]   + bs0;
        float v1 = cfr[mt][nt][r2*2+1] + bs1;
        unsigned pk = (unsigned)f2b(v0) | ((unsigned)f2b(v1)<<16);
        *(unsigned*)(smem + (size_t)t_l*136 + co_l) = pk;
      }
    }
  }
  __syncthreads();
  int row0 = tid>>6, lane2 = tid&63;
  size_t gbase = (((size_t)b*512 + tt*128)*8 + f)*512 + cot*128;
  for (int p=0; p<32; ++p){
    int t_l = p*4 + row0;
    unsigned v = *(const unsigned*)(smem + (size_t)t_l*136 + lane2*2);
    *(unsigned*)(gt + gbase + (size_t)t_l*8*512 + lane2*2) = v;
  }
}

// ---------------- sequential LSTM scan (R8 + batched bfr/Gl loads) ----------
__global__ __launch_bounds__(512,2) void k_lstm_scan(
    const u16* __restrict__ gt, const u16* __restrict__ Whb,
    u16* __restrict__ hs)
{
  __shared__ __align__(16) u16 Bl[6144+16];
  __shared__ float Gl[512*9];
  int b = blockIdx.x;
  int tid = threadIdx.x, w = tid>>6, L = tid&63, q = L>>4, n = L&15;
  int ch = tid>>2, fa = tid&3, fb = fa|4;
  for (int i = tid; i < 6144+16; i += 512) Bl[i] = 0;
  bf16x8 afr[48];
  #pragma unroll
  for (int mt=0; mt<4; ++mt){
    const u16* ap = Whb + (size_t)(w*64 + mt*16 + n)*384 + q*8;
    #pragma unroll
    for (int kt=0; kt<12; ++kt)
      afr[mt*12+kt] = *(const bf16x8*)(ap + kt*32);
  }
  int sa[6];
  #pragma unroll
  for (int i2=0;i2<2;++i2){
    int fi = i2 ? fb : fa;
    #pragma unroll
    for (int kf=0;kf<3;++kf){
      int ff = fi + 1 - kf;
      int k = ch*3 + kf;
      sa[i2*3+kf] = (ff>=0 && ff<8)
          ? (((k>>5)*4 + ((k>>3)&3))*128 + ff*8 + (k&7))
          : (6144 + (tid&7));
    }
  }
  float c0 = 0.f, c1 = 0.f;
  __syncthreads();
  const size_t gbase = (size_t)b*512;
  const u16* pa = gt + gbase*4096 + fa*512 + ch;
  const u16* pb = gt + gbase*4096 + fb*512 + ch;
  u16 gc[8];
  #pragma unroll
  for (int g=0; g<4; ++g){ gc[g] = pa[g*128]; gc[4+g] = pb[g*128]; }
  for (int t=0; t<TT; ++t){
    u16 gn[8];
    {
      int tc = (t+1 < TT) ? (t+1) : t;
      const u16* qa = pa + (size_t)tc*4096;
      const u16* qb = pb + (size_t)tc*4096;
      #pragma unroll
      for (int g=0; g<4; ++g){ gn[g] = qa[g*128]; gn[4+g] = qb[g*128]; }
    }
    // ---- batched B-fragment loads: all 12 ds_read_b128 issued before MFMAs
    bf16x8 bfr[12];
    #pragma unroll
    for (int kt=0; kt<12; ++kt)
      bfr[kt] = *(const bf16x8*)(Bl + ((kt*4+q)*16 + n)*8);
    f32x4 cfr[4];
    #pragma unroll
    for (int mt=0; mt<4; ++mt){ cfr[mt][0]=0.f; cfr[mt][1]=0.f; cfr[mt][2]=0.f; cfr[mt][3]=0.f; }
    #pragma unroll
    for (int kt=0; kt<12; ++kt){
      #pragma unroll
      for (int mt=0; mt<4; ++mt)
        cfr[mt] = __builtin_amdgcn_mfma_f32_16x16x32_bf16(afr[mt*12+kt], bfr[kt], cfr[mt], 0,0,0);
    }
    if (n < 8){
      #pragma unroll
      for (int mt=0; mt<4; ++mt){
        int co = w*64 + mt*16 + q*4;
        #pragma unroll
        for (int r=0; r<4; ++r) Gl[(co+r)*9 + n] = cfr[mt][r];
      }
    }
    bar_lds();
    // ---- batched gate loads into locals, then the transcendental chains
    float gv[8];
    gv[0] = Gl[ ch      *9 + fa]; gv[1] = Gl[(128+ch)*9 + fa];
    gv[2] = Gl[(256+ch)*9 + fa]; gv[3] = Gl[(384+ch)*9 + fa];
    gv[4] = Gl[ ch      *9 + fb]; gv[5] = Gl[(128+ch)*9 + fb];
    gv[6] = Gl[(256+ch)*9 + fb]; gv[7] = Gl[(384+ch)*9 + fb];
    float i0 = gv[0] + b2f(gc[0]);
    float f0 = gv[1] + b2f(gc[1]);
    float o0 = gv[2] + b2f(gc[2]);
    float g0 = gv[3] + b2f(gc[3]);
    float i1 = gv[4] + b2f(gc[4]);
    float f1 = gv[5] + b2f(gc[5]);
    float o1 = gv[6] + b2f(gc[6]);
    float g1 = gv[7] + b2f(gc[7]);
    c0 = sigm_(f0)*c0 + sigm_(i0)*tanh_(g0);
    c1 = sigm_(f1)*c1 + sigm_(i1)*tanh_(g1);
    float h0 = sigm_(o0)*tanh_(c0);
    float h1 = sigm_(o1)*tanh_(c1);
    u16 hb0 = f2b(h0), hb1 = f2b(h1);
    u16* op = hs + ((gbase + t)*128 + ch)*8;
    op[fa] = hb0;
    op[fb] = hb1;
    Bl[sa[0]] = hb0; Bl[sa[1]] = hb0; Bl[sa[2]] = hb0;
    Bl[sa[3]] = hb1; Bl[sa[4]] = hb1; Bl[sa[5]] = hb1;
    bar_lds();
    #pragma unroll
    for (int g=0; g<8; ++g) gc[g] = gn[g];
  }
}

// ---------------- batched u16 transpose [b][R][C] -> [b][C][R] --------------
__global__ __launch_bounds__(256) void k_transpose_u16(
    const u16* __restrict__ in, u16* __restrict__ out, int R, int C)
{
  __shared__ u16 tile[32][33];
  int b = blockIdx.z;
  const u16* ip = in  + (size_t)b*R*C;
  u16*       op = out + (size_t)b*R*C;
  int c0 = blockIdx.x*32, r0 = blockIdx.y*32;
  #pragma unroll
  for (int i = threadIdx.y; i < 32; i += 8)
    tile[i][threadIdx.x] = ip[(size_t)(r0+i)*C + (c0+threadIdx.x)];
  __syncthreads();
  #pragma unroll
  for (int i = threadIdx.y; i < 32; i += 8)
    op[(size_t)(c0+i)*R + (r0+threadIdx.x)] = tile[threadIdx.x][i];
}

// ---------------- dec1 scalar: convT + sigmoid + x*mask ---------------------
__global__ __launch_bounds__(128) void k_convT(
    const u16* __restrict__ inA, int C1,
    const u16* __restrict__ inB, int C2,
    const float* __restrict__ w, const float* __restrict__ bias,
    const float* __restrict__ xorig, float* __restrict__ fout,
    int Cout, int Hin)
{
  int Hout = Hin*2;
  int blk = blockIdx.x;
  int y = blk % Hout; blk /= Hout;
  int co = blk % Cout; int b = blk / Cout;
  int t0 = threadIdx.x*4;
  int Cin = C1 + C2;
  int kh0, hi0, kh1 = -1, hi1 = 0;
  if ((y&1)==0){ kh0 = 1; hi0 = y>>1; }
  else { kh0 = 2; hi0 = (y-1)>>1; int h1 = (y+1)>>1; if (h1 < Hin){ kh1 = 0; hi1 = h1; } }
  float a0=0.f,a1=0.f,a2=0.f,a3=0.f;
  for (int ci=0; ci<Cin; ++ci){
    const u16* ib = (ci<C1) ? inA + (size_t)(b*C1+ci)*Hin*WW
                            : inB + (size_t)(b*C2+(ci-C1))*Hin*WW;
    const float* wc = w + ((size_t)ci*Cout + co)*9;
    {
      float w0 = wc[kh0*3+0], w1 = wc[kh0*3+1], w2 = wc[kh0*3+2];
      const u16* row = ib + (size_t)hi0*WW + t0;
      ushort4 xc = *(const ushort4*)row;
      float x0=b2f(xc.x), x1=b2f(xc.y), x2=b2f(xc.z), x3=b2f(xc.w);
      float xm = (t0==0)    ? 0.f : b2f(row[-1]);
      float xp = (t0+4>=WW) ? 0.f : b2f(row[4]);
      a0 += w2*xm + w1*x0 + w0*x1;
      a1 += w2*x0 + w1*x1 + w0*x2;
      a2 += w2*x1 + w1*x2 + w0*x3;
      a3 += w2*x2 + w1*x3 + w0*xp;
    }
    if (kh1 >= 0){
      float w0 = wc[0], w1 = wc[1], w2 = wc[2];
      const u16* row = ib + (size_t)hi1*WW + t0;
      ushort4 xc = *(const ushort4*)row;
      float x0=b2f(xc.x), x1=b2f(xc.y), x2=b2f(xc.z), x3=b2f(xc.w);
      float xm = (t0==0)    ? 0.f : b2f(row[-1]);
      float xp = (t0+4>=WW) ? 0.f : b2f(row[4]);
      a0 += w2*xm + w1*x0 + w0*x1;
      a1 += w2*x0 + w1*x1 + w0*x2;
      a2 += w2*x1 + w1*x2 + w0*x3;
      a3 += w2*x2 + w1*x3 + w0*xp;
    }
  }
  size_t opos = ((size_t)((b*Cout+co)*Hout + y))*WW + t0;
  float bi = bias[co];
  const float4 xv = *(const float4*)(xorig + ((size_t)(b*256 + y))*WW + t0);
  float4 o;
  o.x = xv.x * sigm_(a0+bi); o.y = xv.y * sigm_(a1+bi);
  o.z = xv.z * sigm_(a2+bi); o.w = xv.w * sigm_(a3+bi);
  *(float4*)(fout + opos) = o;
}

// ---------------------------------------------------------------------------
extern "C" void kernel_launch(void* const* d_in, const int* in_sizes, int n_in,
                              void* d_out, int out_size, void* d_ws, size_t ws_size,
                              hipStream_t stream) {
  const float* x = (const float*)d_in[0];
  struct Blk { const float *w,*b,*g,*be,*m,*v; };
  auto grab = [&](int p){ return Blk{ (const float*)d_in[p], (const float*)d_in[p+1],
                                      (const float*)d_in[p+2], (const float*)d_in[p+3],
                                      (const float*)d_in[p+4], (const float*)d_in[p+5] }; };
  Blk enc1 = grab(1), enc2 = grab(7), enc3 = grab(13), enc4 = grab(19), enc5 = grab(25);
  const float* lstm_w = (const float*)d_in[31];
  const float* lstm_b = (const float*)d_in[32];
  Blk dec5 = grab(33), dec4 = grab(39), dec3 = grab(45), dec2 = grab(51);
  const float* dec1_w = (const float*)d_in[57];
  const float* dec1_b = (const float*)d_in[58];

  // ---- 228 MiB arena, lifetime-aliased ----
  char* ws = (char*)d_ws;
  #define MBOF(x) ((size_t)(x)*1048576ULL)
  u16*   xlog = (u16*)  (ws + MBOF(0));
  u16*   Wxb  = (u16*)  (ws + MBOF(0));
  u16*   Whb  = (u16*)  (ws + MBOF(1));
  char*  P0   =          ws + 1572864;
  u16*   e1   = (u16*)  (ws + MBOF(4));
  u16*   e2   = (u16*)  (ws + MBOF(36));
  u16*   e3   = (u16*)  (ws + MBOF(68));
  u16*   e4   = (u16*)  (ws + MBOF(100));
  u16*   e5   = (u16*)  (ws + MBOF(132));
  u16*   hst  = (u16*)  (ws + MBOF(132));
  u16*   lout = (u16*)  (ws + MBOF(148));
  u16*   gt   = (u16*)  (ws + MBOF(164));
  u16*   d5   = (u16*)  (ws + MBOF(164));
  u16*   d4   = (u16*)  (ws + MBOF(132));
  u16*   d3   = (u16*)  (ws + MBOF(196));
  u16*   d2   = (u16*)  (ws + MBOF(164));

  u16* encA2 = (u16*)(P0 + 0);       u16* encA3 = (u16*)(P0 + 12288);
  u16* encA4 = (u16*)(P0 + 49152);   u16* encA5 = (u16*)(P0 + 196608);
  u16* decE5 = (u16*)(P0 + 786432);  u16* decO5 = (u16*)(P0 + 884736);
  u16* decE4 = (u16*)(P0 + 1081344); u16* decO4 = (u16*)(P0 + 1179648);
  u16* decE3 = (u16*)(P0 + 1376256); u16* decO3 = (u16*)(P0 + 1400832);
  u16* decE2 = (u16*)(P0 + 1449984); u16* decO2 = (u16*)(P0 + 1456128);
  float* bE2 = (float*)(P0 + 1468416); float* bE3 = (float*)(P0 + 1469440);
  float* bE4 = (float*)(P0 + 1470464); float* bE5 = (float*)(P0 + 1471488);
  float* bD5 = (float*)(P0 + 1472512); float* bD4 = (float*)(P0 + 1473536);
  float* bD3 = (float*)(P0 + 1474560); float* bD2 = (float*)(P0 + 1475584);

  // 1. log10 + enc1 (scalar)
  { int n = BB*256*WW; k_log10<<<(n+255)/256, 256, 0, stream>>>(x, xlog, n); }
  k_conv_enc<<<BB*16*128, 128, 0, stream>>>(xlog, enc1.w, enc1.b, enc1.g, enc1.be, enc1.m, enc1.v, e1, 1, 16, 256, 128);
  // 2. weight prep (xlog region dead now)
  k_prep_w<<<512, 256, 0, stream>>>(lstm_w, Wxb, Whb);
  k_prep_enc<<<32,  256, 0, stream>>>(enc2.w, enc2.b, enc2.g, enc2.be, enc2.m, enc2.v, encA2, bE2, 16, 32, 64);
  k_prep_enc<<<64,  256, 0, stream>>>(enc3.w, enc3.b, enc3.g, enc3.be, enc3.m, enc3.v, encA3, bE3, 32, 64, 96);
  k_prep_enc<<<128, 256, 0, stream>>>(enc4.w, enc4.b, enc4.g, enc4.be, enc4.m, enc4.v, encA4, bE4, 64, 128, 192);
  k_prep_enc<<<256, 256, 0, stream>>>(enc5.w, enc5.b, enc5.g, enc5.be, enc5.m, enc5.v, encA5, bE5, 128, 256, 384);
  k_prep_dec<<<128, 256, 0, stream>>>(dec5.w, dec5.b, dec5.g, dec5.be, dec5.m, dec5.v, decE5, decO5, bD5, 128, 128);
  k_prep_dec<<<64,  256, 0, stream>>>(dec4.w, dec4.b, dec4.g, dec4.be, dec4.m, dec4.v, decE4, decO4, bD4, 256, 64);
  k_prep_dec<<<32,  256, 0, stream>>>(dec3.w, dec3.b, dec3.g, dec3.be, dec3.m, dec3.v, decE3, decO3, bD3, 128, 32);
  k_prep_dec<<<16,  256, 0, stream>>>(dec2.w, dec2.b, dec2.g, dec2.be, dec2.m, dec2.v, decE2, decO2, bD2, 64, 16);
  // 3. encoder (MFMA implicit GEMM)
  k_conv_mfma<2,2,1,4, 16,0, 32,128,0,1><<<BB*64*4,   256, 0, stream>>>(e1, e1, encA2, encA2, bE2, e2);
  k_conv_mfma<4,2,1,4, 32,0, 64, 64,0,1><<<BB*32*4,   256, 0, stream>>>(e2, e2, encA3, encA3, bE3, e3);
  k_conv_mfma<4,4,2,2, 64,0,128, 32,0,1><<<BB*16*4,   256, 0, stream>>>(e3, e3, encA4, encA4, bE4, e4);
  k_conv_mfma<4,4,2,2,128,0,256, 16,0,2><<<BB*8*2*4,  256, 0, stream>>>(e4, e4, encA5, encA5, bE5, e5);
  // 4. LSTM
  k_xconv_mfma<<<BB*8*16, 256, 0, stream>>>(e5, Wxb, lstm_b, gt);
  k_lstm_scan<<<BB, 512, 0, stream>>>(gt, Whb, hst);
  k_transpose_u16<<<dim3(1024/32, 512/32, BB), dim3(32,8), 0, stream>>>(hst, lout, 512, 1024);
  // 5. decoder (MFMA implicit GEMM) + dec1 scalar
  k_conv_mfma<4,4,2,2,128,  0,128,  8,1,1><<<BB*16*4,  256, 0, stream>>>(lout, lout, decE5, decO5, bD5, d5);
  k_conv_mfma<4,2,1,4,128,128, 64, 16,1,1><<<BB*32*4,  256, 0, stream>>>(d5, e4, decE4, decO4, bD4, d4);
  k_conv_mfma<2,2,1,4, 64, 64, 32, 32,1,1><<<BB*64*4,  256, 0, stream>>>(d4, e3, decE3, decO3, bD3, d3);
  k_conv_mfma<1,2,1,4, 32, 32, 16, 64,1,1><<<BB*128*4, 256, 0, stream>>>(d3, e2, decE2, decO2, bD2, d2);
  k_convT<<<BB*1*256, 128, 0, stream>>>(d2, 16, e1, 16, dec1_w, dec1_b, x, (float*)d_out, 1, 128);
}

// Round 10
// 1939.172 us; speedup vs baseline: 1.0491x; 1.0282x over previous
//
#include <hip/hip_runtime.h>
#include <math.h>

// ---------------------------------------------------------------------------
// AudioUNet5ConvLSTM — bf16 storage/f32 accum; MFMA for LSTM GEMMs and all
// inner conv/convT layers (implicit GEMM, BN folded into bf16 weights).
// R10: R9 + ONE change — XOR-swizzled LDS staging in k_conv_mfma and
// k_xconv_mfma: col = k ^ (((row>>4)&3)<<3). Breaks the seg-degenerate
// 16-way write conflicts (stride 16*40 ≡ 0 mod 32 banks) down to ~4-way.
// Address-level static swizzle — no dynamic register indexing (R5 lesson).
// ---------------------------------------------------------------------------

#define WW 512
#define BB 16
#define TT 512

typedef unsigned short u16;
typedef __attribute__((ext_vector_type(8))) short bf16x8;
typedef __attribute__((ext_vector_type(4))) float f32x4;

__device__ __forceinline__ float sigm_(float x){ return 1.f/(1.f+__expf(-x)); }
__device__ __forceinline__ float tanh_(float x){ return 1.f - 2.f/(1.f+__expf(2.f*x)); }
__device__ __forceinline__ float b2f(u16 u){ return __uint_as_float(((unsigned)u)<<16); }
__device__ __forceinline__ u16 f2b(float f){
  unsigned x = __float_as_uint(f);
  return (u16)((x + 0x7fffu + ((x>>16)&1u)) >> 16);   // RNE
}
// LDS-only barrier: no vmcnt drain (global prefetch/stores stay in flight)
__device__ __forceinline__ void bar_lds(){
  asm volatile("s_waitcnt lgkmcnt(0)\n\ts_barrier" ::: "memory");
}

// ---------------- elementwise log10(x + 1e-8) -> bf16 ----------------
__global__ void k_log10(const float* __restrict__ x, u16* __restrict__ y, int n){
  int i = blockIdx.x*256 + threadIdx.x;
  if (i < n) y[i] = f2b(log10f(x[i] + 1e-8f));
}

// ---------------- enc1 (Cin=1) scalar: conv s(2,1) + BN + LReLU -------------
__global__ __launch_bounds__(128) void k_conv_enc(
    const u16* __restrict__ in, const float* __restrict__ w,
    const float* __restrict__ bias, const float* __restrict__ bg,
    const float* __restrict__ bb_, const float* __restrict__ bm,
    const float* __restrict__ bv, u16* __restrict__ out,
    int Cin, int Cout, int Hin, int Hout)
{
  int blk = blockIdx.x;
  int ho = blk % Hout; blk /= Hout;
  int co = blk % Cout; int b = blk / Cout;
  int t0 = threadIdx.x*4;
  float a0=0.f,a1=0.f,a2=0.f,a3=0.f;
  const float* wb = w + (size_t)co*Cin*9;
  for (int ci=0; ci<Cin; ++ci){
    const u16* ib = in + (size_t)(b*Cin+ci)*Hin*WW;
    const float* wc = wb + ci*9;
    #pragma unroll
    for (int kh=0; kh<3; ++kh){
      int hi = 2*ho + kh - 1;
      if (hi < 0 || hi >= Hin) continue;
      float w0 = wc[kh*3+0], w1 = wc[kh*3+1], w2 = wc[kh*3+2];
      const u16* row = ib + (size_t)hi*WW + t0;
      ushort4 xc = *(const ushort4*)row;
      float x0=b2f(xc.x), x1=b2f(xc.y), x2=b2f(xc.z), x3=b2f(xc.w);
      float xm = (t0==0)    ? 0.f : b2f(row[-1]);
      float xp = (t0+4>=WW) ? 0.f : b2f(row[4]);
      a0 += w0*xm + w1*x0 + w2*x1;
      a1 += w0*x0 + w1*x1 + w2*x2;
      a2 += w0*x1 + w1*x2 + w2*x3;
      a3 += w0*x2 + w1*x3 + w2*xp;
    }
  }
  float sc = bg[co]*rsqrtf(bv[co]+1e-5f);
  float sh = bb_[co] - bm[co]*sc + bias[co]*sc;
  float r0 = sc*a0+sh, r1 = sc*a1+sh, r2 = sc*a2+sh, r3 = sc*a3+sh;
  r0 = (r0>=0.f)?r0:0.2f*r0; r1 = (r1>=0.f)?r1:0.2f*r1;
  r2 = (r2>=0.f)?r2:0.2f*r2; r3 = (r3>=0.f)?r3:0.2f*r3;
  *(ushort4*)(out + ((size_t)((b*Cout+co)*Hout+ho))*WW + t0) =
      make_ushort4(f2b(r0), f2b(r1), f2b(r2), f2b(r3));
}

// ---------------- prep: encoder weights -> A[kw][co][KPAD] bf16, BN folded --
__global__ __launch_bounds__(256) void k_prep_enc(
    const float* __restrict__ w, const float* __restrict__ b,
    const float* __restrict__ g, const float* __restrict__ be,
    const float* __restrict__ m, const float* __restrict__ v,
    u16* __restrict__ A, float* __restrict__ bias2, int Cin, int Cout, int KPAD)
{
  int co = blockIdx.x;
  float sc = g[co]*rsqrtf(v[co]+1e-5f);
  if (threadIdx.x == 0) bias2[co] = be[co] - m[co]*sc + b[co]*sc;
  for (int idx = threadIdx.x; idx < 3*KPAD; idx += 256){
    int kw = idx / KPAD, k = idx - kw*KPAD;
    float val = 0.f;
    if (k < Cin*3){ int ci = k/3, kh = k - ci*3; val = w[(((size_t)co*Cin+ci)*3+kh)*3+kw]*sc; }
    A[(size_t)(kw*Cout+co)*KPAD + k] = f2b(val);
  }
}

// ---------------- prep: decoder weights (torch [Cin][Cout][3][3]) -----------
__global__ __launch_bounds__(256) void k_prep_dec(
    const float* __restrict__ w, const float* __restrict__ b,
    const float* __restrict__ g, const float* __restrict__ be,
    const float* __restrict__ m, const float* __restrict__ v,
    u16* __restrict__ AE, u16* __restrict__ AO, float* __restrict__ bias2,
    int Cin, int Cout)
{
  int co = blockIdx.x;
  float sc = g[co]*rsqrtf(v[co]+1e-5f);
  if (threadIdx.x == 0) bias2[co] = be[co] - m[co]*sc + b[co]*sc;
  for (int idx = threadIdx.x; idx < 3*Cin; idx += 256){
    int kw = idx / Cin, ci = idx - kw*Cin;
    const float* wp = w + ((size_t)ci*Cout + co)*9;
    AE[(size_t)(kw*Cout+co)*Cin + ci]          = f2b(wp[3+kw]*sc);   // kh=1
    AO[((size_t)(kw*Cout+co)*Cin + ci)*2 + 0]  = f2b(wp[6+kw]*sc);   // kh=2
    AO[((size_t)(kw*Cout+co)*Cin + ci)*2 + 1]  = f2b(wp[0+kw]*sc);   // kh=0
  }
}

// ---------------- implicit-GEMM MFMA conv / convT (XOR-swizzled staging) ----
// LDS layout: element (row,k) at sB[row*40 + (k ^ (((row>>4)&3)<<3))].
template<int MT,int NT,int WMW,int WNW,int C1,int C2,int COUT,int HIN,int MODE,int MTL>
__global__ __launch_bounds__(256,2) void k_conv_mfma(
    const u16* __restrict__ inA, const u16* __restrict__ inB,
    const u16* __restrict__ AE, const u16* __restrict__ AO,
    const float* __restrict__ bias2, u16* __restrict__ out)
{
  constexpr int CIN  = C1 + C2;
  constexpr int HOUT = MODE ? HIN*2 : HIN/2;
  constexpr int KPAD0 = MODE ? CIN : ((C1*3+31)/32)*32;
  constexpr int LDK = 40;
  __shared__ __align__(16) u16 sB[130*LDK];
  int bi = blockIdx.x;
  int tt = bi & 3; bi >>= 2;
  int mt0 = 0;
  if (MTL == 2){ mt0 = bi & 1; bi >>= 1; }
  int ho = bi % HOUT, b = bi / HOUT;
  int t0 = tt*128;
  int tid = threadIdx.x;
  int w = tid>>6, L = tid&63, q = L>>4, n = L&15;
  int wm = w / WNW, wn = w % WNW;
  int co_base = (mt0*WMW + wm)*MT*16;
  int no = wn*NT*16;
  int odd = MODE ? (ho & 1) : 0;
  int nch     = MODE ? (odd ? CIN/16 : CIN/32) : KPAD0/32;
  int kstride = MODE ? (odd ? 2*CIN : CIN) : KPAD0;
  const u16* Ap = (MODE && odd) ? AO : AE;
  int kloc = tid>>3, seg = tid&7;
  f32x4 cfr[MT][NT];
  #pragma unroll
  for (int mt=0; mt<MT; ++mt)
    #pragma unroll
    for (int nt=0; nt<NT; ++nt){ cfr[mt][nt][0]=0.f; cfr[mt][nt][1]=0.f; cfr[mt][nt][2]=0.f; cfr[mt][nt][3]=0.f; }

  for (int kk=0; kk<nch; ++kk){
    int k = kk*32 + kloc;
    const u16* src = nullptr;
    if (MODE == 0){
      int ci = k/3, kh = k - 3*ci;
      int hi = 2*ho + kh - 1;
      if (k < C1*3 && hi >= 0 && hi < HIN)
        src = inA + ((size_t)(b*C1+ci)*HIN + hi)*WW;
    } else {
      int ci, hi;
      if (!odd){ ci = k; hi = ho>>1; }
      else { ci = k>>1; hi = (k&1) ? ((ho+1)>>1) : ((ho-1)>>1); }
      if (hi < HIN)
        src = (ci < C1) ? inA + ((size_t)(b*C1+ci)*HIN + hi)*WW
                        : inB + ((size_t)(b*C2+(ci-C1))*HIN + hi)*WW;
    }
    uint4 va = make_uint4(0,0,0,0), vb = make_uint4(0,0,0,0);
    u16 hl = 0, hr = 0;
    if (src){
      const u16* p = src + t0 + seg*16;
      va = *(const uint4*)p; vb = *(const uint4*)(p+8);
      if (seg==0 && t0 > 0)      hl = src[t0-1];
      if (seg==1 && t0+128 < WW) hr = src[t0+128];
    }
    __syncthreads();
    {
      const u16* s = (const u16*)&va;
      #pragma unroll
      for (int c=0;c<8;++c){
        int row = 1+seg*16+c;
        sB[row*LDK + (kloc ^ (((row>>4)&3)<<3))] = s[c];
      }
      s = (const u16*)&vb;
      #pragma unroll
      for (int c=0;c<8;++c){
        int row = 9+seg*16+c;
        sB[row*LDK + (kloc ^ (((row>>4)&3)<<3))] = s[c];
      }
      if (seg==0) sB[0*LDK + kloc]   = hl;     // row 0:  swizzle grp 0
      if (seg==1) sB[129*LDK + kloc] = hr;     // row 129: (129>>4)&3 == 0
    }
    __syncthreads();
    #pragma unroll
    for (int kw=0; kw<3; ++kw){
      int tsh = MODE ? (2-kw) : kw;
      bf16x8 bfr[NT];
      #pragma unroll
      for (int nt=0; nt<NT; ++nt){
        int row = no + nt*16 + n + tsh;
        bfr[nt] = *(const bf16x8*)(sB + (size_t)row*LDK + ((q ^ ((row>>4)&3))<<3));
      }
      #pragma unroll
      for (int mt=0; mt<MT; ++mt){
        bf16x8 a = *(const bf16x8*)(Ap + ((size_t)(kw*COUT) + co_base + mt*16 + n)*kstride + kk*32 + q*8);
        #pragma unroll
        for (int nt=0; nt<NT; ++nt)
          cfr[mt][nt] = __builtin_amdgcn_mfma_f32_16x16x32_bf16(a, bfr[nt], cfr[mt][nt], 0,0,0);
      }
    }
  }
  #pragma unroll
  for (int mt=0; mt<MT; ++mt){
    #pragma unroll
    for (int r=0; r<4; ++r){
      int co = co_base + mt*16 + q*4 + r;
      float bs = bias2[co];
      #pragma unroll
      for (int nt=0; nt<NT; ++nt){
        float vv = cfr[mt][nt][r] + bs;
        vv = MODE ? fmaxf(vv, 0.f) : ((vv>=0.f)?vv:0.2f*vv);
        int t = t0 + no + nt*16 + n;
        out[((size_t)(b*COUT+co)*HOUT + ho)*WW + t] = f2b(vv);
      }
    }
  }
}

// ---------------- prep: pack lstm weights (kw=1 col) to bf16 GEMM layout ----
__global__ __launch_bounds__(256) void k_prep_w(
    const float* __restrict__ lstm_w, u16* __restrict__ Wxb, u16* __restrict__ Whb)
{
  int co = blockIdx.x;
  for (int k = threadIdx.x; k < 1152; k += 256){
    if (k < 768){
      int ci = k/3, kf = k - ci*3;
      Wxb[(size_t)co*768 + k] = f2b(lstm_w[((size_t)co*384 + ci)*9 + kf*3 + 1]);
    } else {
      int kh = k - 768;
      int ci = kh/3, kf = kh - ci*3;
      Whb[(size_t)co*384 + kh] = f2b(lstm_w[((size_t)co*384 + 256 + ci)*9 + kf*3 + 1]);
    }
  }
}

// ---------------- LSTM x-part as MFMA GEMM (XOR-swizzled staging) -----------
__global__ __launch_bounds__(256,3) void k_xconv_mfma(
    const u16* __restrict__ e5, const u16* __restrict__ Wxb,
    const float* __restrict__ bias, u16* __restrict__ gt)
{
  __shared__ __align__(16) u16 smem[128*136];
  int bi = blockIdx.x;
  int tt = bi & 3, cot = (bi>>2) & 3, f = (bi>>4) & 7, b = bi>>7;
  int tid = threadIdx.x, w = tid>>6, L = tid&63, q = L>>4, n = L&15;
  int co_off = (w>>1)*64, t_off = (w&1)*64;
  int sr = tid>>3, sseg = tid&7;
  f32x4 cfr[4][4];
  #pragma unroll
  for (int i=0;i<4;++i)
    #pragma unroll
    for (int j=0;j<4;++j){ cfr[i][j][0]=0.f; cfr[i][j][1]=0.f; cfr[i][j][2]=0.f; cfr[i][j][3]=0.f; }
  const u16* e5b = e5 + (size_t)b*256*8*WW + tt*128 + sseg*16;
  const u16* ap0 = Wxb + (size_t)(cot*128 + co_off + n)*768 + q*8;

  for (int kk=0; kk<24; ++kk){
    int k0 = kk*32;
    {
      int k = k0 + sr;
      int ci = k/3, kf = k - ci*3, fi = f + kf - 1;
      union { uint4 v[2]; u16 s[16]; } uu;
      if (fi >= 0 && fi < 8){
        const u16* src = e5b + ((size_t)ci*8 + fi)*WW;
        uu.v[0] = *(const uint4*)src;
        uu.v[1] = *(const uint4*)(src+8);
      } else {
        uu.v[0] = make_uint4(0,0,0,0); uu.v[1] = make_uint4(0,0,0,0);
      }
      #pragma unroll
      for (int c=0;c<16;++c){
        int row = sseg*16+c;                       // row>>4 == sseg (c<16)
        smem[row*40 + (sr ^ ((sseg&3)<<3))] = uu.s[c];
      }
    }
    __syncthreads();
    bf16x8 bfr[4];
    #pragma unroll
    for (int nt=0; nt<4; ++nt){
      int row = t_off + nt*16 + n;
      bfr[nt] = *(const bf16x8*)(smem + (size_t)row*40 + ((q ^ ((row>>4)&3))<<3));
    }
    #pragma unroll
    for (int mt=0; mt<4; ++mt){
      bf16x8 a = *(const bf16x8*)(ap0 + (size_t)mt*16*768 + k0);
      #pragma unroll
      for (int nt=0; nt<4; ++nt)
        cfr[mt][nt] = __builtin_amdgcn_mfma_f32_16x16x32_bf16(a, bfr[nt], cfr[mt][nt], 0,0,0);
    }
    __syncthreads();
  }
  #pragma unroll
  for (int mt=0; mt<4; ++mt){
    #pragma unroll
    for (int r2=0; r2<2; ++r2){
      int co_l = co_off + mt*16 + q*4 + r2*2;
      float bs0 = bias[cot*128 + co_l], bs1 = bias[cot*128 + co_l + 1];
      #pragma unroll
      for (int nt=0; nt<4; ++nt){
        int t_l = t_off + nt*16 + n;
        float v0 = cfr[mt][nt][r2*2]   + bs0;
        float v1 = cfr[mt][nt][r2*2+1] + bs1;
        unsigned pk = (unsigned)f2b(v0) | ((unsigned)f2b(v1)<<16);
        *(unsigned*)(smem + (size_t)t_l*136 + co_l) = pk;
      }
    }
  }
  __syncthreads();
  int row0 = tid>>6, lane2 = tid&63;
  size_t gbase = (((size_t)b*512 + tt*128)*8 + f)*512 + cot*128;
  for (int p=0; p<32; ++p){
    int t_l = p*4 + row0;
    unsigned v = *(const unsigned*)(smem + (size_t)t_l*136 + lane2*2);
    *(unsigned*)(gt + gbase + (size_t)t_l*8*512 + lane2*2) = v;
  }
}

// ---------------- sequential LSTM scan (R9 exact) ---------------------------
__global__ __launch_bounds__(512,2) void k_lstm_scan(
    const u16* __restrict__ gt, const u16* __restrict__ Whb,
    u16* __restrict__ hs)
{
  __shared__ __align__(16) u16 Bl[6144+16];
  __shared__ float Gl[512*9];
  int b = blockIdx.x;
  int tid = threadIdx.x, w = tid>>6, L = tid&63, q = L>>4, n = L&15;
  int ch = tid>>2, fa = tid&3, fb = fa|4;
  for (int i = tid; i < 6144+16; i += 512) Bl[i] = 0;
  bf16x8 afr[48];
  #pragma unroll
  for (int mt=0; mt<4; ++mt){
    const u16* ap = Whb + (size_t)(w*64 + mt*16 + n)*384 + q*8;
    #pragma unroll
    for (int kt=0; kt<12; ++kt)
      afr[mt*12+kt] = *(const bf16x8*)(ap + kt*32);
  }
  int sa[6];
  #pragma unroll
  for (int i2=0;i2<2;++i2){
    int fi = i2 ? fb : fa;
    #pragma unroll
    for (int kf=0;kf<3;++kf){
      int ff = fi + 1 - kf;
      int k = ch*3 + kf;
      sa[i2*3+kf] = (ff>=0 && ff<8)
          ? (((k>>5)*4 + ((k>>3)&3))*128 + ff*8 + (k&7))
          : (6144 + (tid&7));
    }
  }
  float c0 = 0.f, c1 = 0.f;
  __syncthreads();
  const size_t gbase = (size_t)b*512;
  const u16* pa = gt + gbase*4096 + fa*512 + ch;
  const u16* pb = gt + gbase*4096 + fb*512 + ch;
  u16 gc[8];
  #pragma unroll
  for (int g=0; g<4; ++g){ gc[g] = pa[g*128]; gc[4+g] = pb[g*128]; }
  for (int t=0; t<TT; ++t){
    u16 gn[8];
    {
      int tc = (t+1 < TT) ? (t+1) : t;
      const u16* qa = pa + (size_t)tc*4096;
      const u16* qb = pb + (size_t)tc*4096;
      #pragma unroll
      for (int g=0; g<4; ++g){ gn[g] = qa[g*128]; gn[4+g] = qb[g*128]; }
    }
    bf16x8 bfr[12];
    #pragma unroll
    for (int kt=0; kt<12; ++kt)
      bfr[kt] = *(const bf16x8*)(Bl + ((kt*4+q)*16 + n)*8);
    f32x4 cfr[4];
    #pragma unroll
    for (int mt=0; mt<4; ++mt){ cfr[mt][0]=0.f; cfr[mt][1]=0.f; cfr[mt][2]=0.f; cfr[mt][3]=0.f; }
    #pragma unroll
    for (int kt=0; kt<12; ++kt){
      #pragma unroll
      for (int mt=0; mt<4; ++mt)
        cfr[mt] = __builtin_amdgcn_mfma_f32_16x16x32_bf16(afr[mt*12+kt], bfr[kt], cfr[mt], 0,0,0);
    }
    if (n < 8){
      #pragma unroll
      for (int mt=0; mt<4; ++mt){
        int co = w*64 + mt*16 + q*4;
        #pragma unroll
        for (int r=0; r<4; ++r) Gl[(co+r)*9 + n] = cfr[mt][r];
      }
    }
    bar_lds();
    float gv[8];
    gv[0] = Gl[ ch      *9 + fa]; gv[1] = Gl[(128+ch)*9 + fa];
    gv[2] = Gl[(256+ch)*9 + fa]; gv[3] = Gl[(384+ch)*9 + fa];
    gv[4] = Gl[ ch      *9 + fb]; gv[5] = Gl[(128+ch)*9 + fb];
    gv[6] = Gl[(256+ch)*9 + fb]; gv[7] = Gl[(384+ch)*9 + fb];
    float i0 = gv[0] + b2f(gc[0]);
    float f0 = gv[1] + b2f(gc[1]);
    float o0 = gv[2] + b2f(gc[2]);
    float g0 = gv[3] + b2f(gc[3]);
    float i1 = gv[4] + b2f(gc[4]);
    float f1 = gv[5] + b2f(gc[5]);
    float o1 = gv[6] + b2f(gc[6]);
    float g1 = gv[7] + b2f(gc[7]);
    c0 = sigm_(f0)*c0 + sigm_(i0)*tanh_(g0);
    c1 = sigm_(f1)*c1 + sigm_(i1)*tanh_(g1);
    float h0 = sigm_(o0)*tanh_(c0);
    float h1 = sigm_(o1)*tanh_(c1);
    u16 hb0 = f2b(h0), hb1 = f2b(h1);
    u16* op = hs + ((gbase + t)*128 + ch)*8;
    op[fa] = hb0;
    op[fb] = hb1;
    Bl[sa[0]] = hb0; Bl[sa[1]] = hb0; Bl[sa[2]] = hb0;
    Bl[sa[3]] = hb1; Bl[sa[4]] = hb1; Bl[sa[5]] = hb1;
    bar_lds();
    #pragma unroll
    for (int g=0; g<8; ++g) gc[g] = gn[g];
  }
}

// ---------------- batched u16 transpose [b][R][C] -> [b][C][R] --------------
__global__ __launch_bounds__(256) void k_transpose_u16(
    const u16* __restrict__ in, u16* __restrict__ out, int R, int C)
{
  __shared__ u16 tile[32][33];
  int b = blockIdx.z;
  const u16* ip = in  + (size_t)b*R*C;
  u16*       op = out + (size_t)b*R*C;
  int c0 = blockIdx.x*32, r0 = blockIdx.y*32;
  #pragma unroll
  for (int i = threadIdx.y; i < 32; i += 8)
    tile[i][threadIdx.x] = ip[(size_t)(r0+i)*C + (c0+threadIdx.x)];
  __syncthreads();
  #pragma unroll
  for (int i = threadIdx.y; i < 32; i += 8)
    op[(size_t)(c0+i)*R + (r0+threadIdx.x)] = tile[threadIdx.x][i];
}

// ---------------- dec1 scalar: convT + sigmoid + x*mask ---------------------
__global__ __launch_bounds__(128) void k_convT(
    const u16* __restrict__ inA, int C1,
    const u16* __restrict__ inB, int C2,
    const float* __restrict__ w, const float* __restrict__ bias,
    const float* __restrict__ xorig, float* __restrict__ fout,
    int Cout, int Hin)
{
  int Hout = Hin*2;
  int blk = blockIdx.x;
  int y = blk % Hout; blk /= Hout;
  int co = blk % Cout; int b = blk / Cout;
  int t0 = threadIdx.x*4;
  int Cin = C1 + C2;
  int kh0, hi0, kh1 = -1, hi1 = 0;
  if ((y&1)==0){ kh0 = 1; hi0 = y>>1; }
  else { kh0 = 2; hi0 = (y-1)>>1; int h1 = (y+1)>>1; if (h1 < Hin){ kh1 = 0; hi1 = h1; } }
  float a0=0.f,a1=0.f,a2=0.f,a3=0.f;
  for (int ci=0; ci<Cin; ++ci){
    const u16* ib = (ci<C1) ? inA + (size_t)(b*C1+ci)*Hin*WW
                            : inB + (size_t)(b*C2+(ci-C1))*Hin*WW;
    const float* wc = w + ((size_t)ci*Cout + co)*9;
    {
      float w0 = wc[kh0*3+0], w1 = wc[kh0*3+1], w2 = wc[kh0*3+2];
      const u16* row = ib + (size_t)hi0*WW + t0;
      ushort4 xc = *(const ushort4*)row;
      float x0=b2f(xc.x), x1=b2f(xc.y), x2=b2f(xc.z), x3=b2f(xc.w);
      float xm = (t0==0)    ? 0.f : b2f(row[-1]);
      float xp = (t0+4>=WW) ? 0.f : b2f(row[4]);
      a0 += w2*xm + w1*x0 + w0*x1;
      a1 += w2*x0 + w1*x1 + w0*x2;
      a2 += w2*x1 + w1*x2 + w0*x3;
      a3 += w2*x2 + w1*x3 + w0*xp;
    }
    if (kh1 >= 0){
      float w0 = wc[0], w1 = wc[1], w2 = wc[2];
      const u16* row = ib + (size_t)hi1*WW + t0;
      ushort4 xc = *(const ushort4*)row;
      float x0=b2f(xc.x), x1=b2f(xc.y), x2=b2f(xc.z), x3=b2f(xc.w);
      float xm = (t0==0)    ? 0.f : b2f(row[-1]);
      float xp = (t0+4>=WW) ? 0.f : b2f(row[4]);
      a0 += w2*xm + w1*x0 + w0*x1;
      a1 += w2*x0 + w1*x1 + w0*x2;
      a2 += w2*x1 + w1*x2 + w0*x3;
      a3 += w2*x2 + w1*x3 + w0*xp;
    }
  }
  size_t opos = ((size_t)((b*Cout+co)*Hout + y))*WW + t0;
  float bi = bias[co];
  const float4 xv = *(const float4*)(xorig + ((size_t)(b*256 + y))*WW + t0);
  float4 o;
  o.x = xv.x * sigm_(a0+bi); o.y = xv.y * sigm_(a1+bi);
  o.z = xv.z * sigm_(a2+bi); o.w = xv.w * sigm_(a3+bi);
  *(float4*)(fout + opos) = o;
}

// ---------------------------------------------------------------------------
extern "C" void kernel_launch(void* const* d_in, const int* in_sizes, int n_in,
                              void* d_out, int out_size, void* d_ws, size_t ws_size,
                              hipStream_t stream) {
  const float* x = (const float*)d_in[0];
  struct Blk { const float *w,*b,*g,*be,*m,*v; };
  auto grab = [&](int p){ return Blk{ (const float*)d_in[p], (const float*)d_in[p+1],
                                      (const float*)d_in[p+2], (const float*)d_in[p+3],
                                      (const float*)d_in[p+4], (const float*)d_in[p+5] }; };
  Blk enc1 = grab(1), enc2 = grab(7), enc3 = grab(13), enc4 = grab(19), enc5 = grab(25);
  const float* lstm_w = (const float*)d_in[31];
  const float* lstm_b = (const float*)d_in[32];
  Blk dec5 = grab(33), dec4 = grab(39), dec3 = grab(45), dec2 = grab(51);
  const float* dec1_w = (const float*)d_in[57];
  const float* dec1_b = (const float*)d_in[58];

  // ---- 228 MiB arena, lifetime-aliased ----
  char* ws = (char*)d_ws;
  #define MBOF(x) ((size_t)(x)*1048576ULL)
  u16*   xlog = (u16*)  (ws + MBOF(0));
  u16*   Wxb  = (u16*)  (ws + MBOF(0));
  u16*   Whb  = (u16*)  (ws + MBOF(1));
  char*  P0   =          ws + 1572864;
  u16*   e1   = (u16*)  (ws + MBOF(4));
  u16*   e2   = (u16*)  (ws + MBOF(36));
  u16*   e3   = (u16*)  (ws + MBOF(68));
  u16*   e4   = (u16*)  (ws + MBOF(100));
  u16*   e5   = (u16*)  (ws + MBOF(132));
  u16*   hst  = (u16*)  (ws + MBOF(132));
  u16*   lout = (u16*)  (ws + MBOF(148));
  u16*   gt   = (u16*)  (ws + MBOF(164));
  u16*   d5   = (u16*)  (ws + MBOF(164));
  u16*   d4   = (u16*)  (ws + MBOF(132));
  u16*   d3   = (u16*)  (ws + MBOF(196));
  u16*   d2   = (u16*)  (ws + MBOF(164));

  u16* encA2 = (u16*)(P0 + 0);       u16* encA3 = (u16*)(P0 + 12288);
  u16* encA4 = (u16*)(P0 + 49152);   u16* encA5 = (u16*)(P0 + 196608);
  u16* decE5 = (u16*)(P0 + 786432);  u16* decO5 = (u16*)(P0 + 884736);
  u16* decE4 = (u16*)(P0 + 1081344); u16* decO4 = (u16*)(P0 + 1179648);
  u16* decE3 = (u16*)(P0 + 1376256); u16* decO3 = (u16*)(P0 + 1400832);
  u16* decE2 = (u16*)(P0 + 1449984); u16* decO2 = (u16*)(P0 + 1456128);
  float* bE2 = (float*)(P0 + 1468416); float* bE3 = (float*)(P0 + 1469440);
  float* bE4 = (float*)(P0 + 1470464); float* bE5 = (float*)(P0 + 1471488);
  float* bD5 = (float*)(P0 + 1472512); float* bD4 = (float*)(P0 + 1473536);
  float* bD3 = (float*)(P0 + 1474560); float* bD2 = (float*)(P0 + 1475584);

  // 1. log10 + enc1 (scalar)
  { int n = BB*256*WW; k_log10<<<(n+255)/256, 256, 0, stream>>>(x, xlog, n); }
  k_conv_enc<<<BB*16*128, 128, 0, stream>>>(xlog, enc1.w, enc1.b, enc1.g, enc1.be, enc1.m, enc1.v, e1, 1, 16, 256, 128);
  // 2. weight prep (xlog region dead now)
  k_prep_w<<<512, 256, 0, stream>>>(lstm_w, Wxb, Whb);
  k_prep_enc<<<32,  256, 0, stream>>>(enc2.w, enc2.b, enc2.g, enc2.be, enc2.m, enc2.v, encA2, bE2, 16, 32, 64);
  k_prep_enc<<<64,  256, 0, stream>>>(enc3.w, enc3.b, enc3.g, enc3.be, enc3.m, enc3.v, encA3, bE3, 32, 64, 96);
  k_prep_enc<<<128, 256, 0, stream>>>(enc4.w, enc4.b, enc4.g, enc4.be, enc4.m, enc4.v, encA4, bE4, 64, 128, 192);
  k_prep_enc<<<256, 256, 0, stream>>>(enc5.w, enc5.b, enc5.g, enc5.be, enc5.m, enc5.v, encA5, bE5, 128, 256, 384);
  k_prep_dec<<<128, 256, 0, stream>>>(dec5.w, dec5.b, dec5.g, dec5.be, dec5.m, dec5.v, decE5, decO5, bD5, 128, 128);
  k_prep_dec<<<64,  256, 0, stream>>>(dec4.w, dec4.b, dec4.g, dec4.be, dec4.m, dec4.v, decE4, decO4, bD4, 256, 64);
  k_prep_dec<<<32,  256, 0, stream>>>(dec3.w, dec3.b, dec3.g, dec3.be, dec3.m, dec3.v, decE3, decO3, bD3, 128, 32);
  k_prep_dec<<<16,  256, 0, stream>>>(dec2.w, dec2.b, dec2.g, dec2.be, dec2.m, dec2.v, decE2, decO2, bD2, 64, 16);
  // 3. encoder (MFMA implicit GEMM)
  k_conv_mfma<2,2,1,4, 16,0, 32,128,0,1><<<BB*64*4,   256, 0, stream>>>(e1, e1, encA2, encA2, bE2, e2);
  k_conv_mfma<4,2,1,4, 32,0, 64, 64,0,1><<<BB*32*4,   256, 0, stream>>>(e2, e2, encA3, encA3, bE3, e3);
  k_conv_mfma<4,4,2,2, 64,0,128, 32,0,1><<<BB*16*4,   256, 0, stream>>>(e3, e3, encA4, encA4, bE4, e4);
  k_conv_mfma<4,4,2,2,128,0,256, 16,0,2><<<BB*8*2*4,  256, 0, stream>>>(e4, e4, encA5, encA5, bE5, e5);
  // 4. LSTM
  k_xconv_mfma<<<BB*8*16, 256, 0, stream>>>(e5, Wxb, lstm_b, gt);
  k_lstm_scan<<<BB, 512, 0, stream>>>(gt, Whb, hst);
  k_transpose_u16<<<dim3(1024/32, 512/32, BB), dim3(32,8), 0, stream>>>(hst, lout, 512, 1024);
  // 5. decoder (MFMA implicit GEMM) + dec1 scalar
  k_conv_mfma<4,4,2,2,128,  0,128,  8,1,1><<<BB*16*4,  256, 0, stream>>>(lout, lout, decE5, decO5, bD5, d5);
  k_conv_mfma<4,2,1,4,128,128, 64, 16,1,1><<<BB*32*4,  256, 0, stream>>>(d5, e4, decE4, decO4, bD4, d4);
  k_conv_mfma<2,2,1,4, 64, 64, 32, 32,1,1><<<BB*64*4,  256, 0, stream>>>(d4, e3, decE3, decO3, bD3, d3);
  k_conv_mfma<1,2,1,4, 32, 32, 16, 64,1,1><<<BB*128*4, 256, 0, stream>>>(d3, e2, decE2, decO2, bD2, d2);
  k_convT<<<BB*1*256, 128, 0, stream>>>(d2, 16, e1, 16, dec1_w, dec1_b, x, (float*)d_out, 1, 128);
}